// Round 6
// baseline (6362.921 us; speedup 1.0000x reference)
//
#include <hip/hip_runtime.h>
#include <math.h>

#define NG 100
#define ND 200
#define NLINE 500
#define NB 300
#define NW 50
#define NS 128
#define NX 500
#define CVIOL 20000.0f
#define NITERS 600
#define PITERS 50
#define NUPAD_MAX 304

// k_pdhg_reg geometry: 512 threads, 16 col-groups x NC=13 cols, 32 row-groups x 16 rows
#define NC   13
#define NUC  208
#define NAG  11      // cols 0..10 per thread pinned in AGPR (16*11 = 176 AGPRs)

// workspace layout (float offsets)
#define OFF_HSP  0          // reg-load layout
#define OFF_HST  114688     // 304*512
#define OFF_B    270336     // 300*300
#define OFF_HWT  360336     // 50*500
#define OFF_QC   385336     // 128*500
#define OFF_QD   449336     // 128*500
#define OFF_RUP  513336     // 100
#define OFF_RDN  513436     // 100
#define OFF_FUP  513536     // 500
#define OFF_FDN  514036     // 500
#define OFF_QE   514536     // 128
#define OFF_STEP 514664     // 1
#define OFF_NU   514665     // int
#define OFF_NUP  514666     // int
#define OFF_NUC  514667     // int (208 = reg kernel, 0 = fallback)
#define OFF_BUS  514668     // 300 ints
#define OFF_BUSW 514968     // 50 ints
#define OFF_UBUS 515018     // 304 ints
#define OFF_C2U  515322     // 300 ints
#define OFF_CUS  515622     // 305 ints
#define OFF_CUL  515927     // 300 ints

// ---------------------------------------------------------------- K1: precompute + unique-bus build
__global__ __launch_bounds__(512) void k_pre(
    const float* __restrict__ p_da, const float* __restrict__ r_up_hat,
    const float* __restrict__ r_down_hat, const float* __restrict__ fup_hat,
    const float* __restrict__ fdn_hat, const float* __restrict__ w_err,
    const float* __restrict__ Pmax, const float* __restrict__ nG,
    const float* __restrict__ nL, const float* __restrict__ nW, float* ws) {
  const int t = threadIdx.x;
  int* bus  = (int*)(ws + OFF_BUS);
  int* busW = (int*)(ws + OFF_BUSW);
  if (t < NG) {
    int bf = 0;
    for (int b = 0; b < NB; ++b) if (nG[b*NG + t] > 0.5f) bf = b;
    bus[t] = bf;
    ws[OFF_RUP + t] = fmaxf(fminf(r_up_hat[t], Pmax[t] - p_da[t]), 0.f);
    ws[OFF_RDN + t] = fmaxf(fminf(r_down_hat[t], p_da[t]), 0.f);
  }
  if (t < ND) {
    int bf = 0;
    for (int b = 0; b < NB; ++b) if (nL[b*ND + t] > 0.5f) bf = b;
    bus[NG + t] = bf;
  }
  if (t < NW) {
    int bf = 0;
    for (int b = 0; b < NB; ++b) if (nW[b*NW + t] > 0.5f) bf = b;
    busW[t] = bf;
  }
  if (t < NLINE) {
    ws[OFF_FUP + t] = fmaxf(fup_hat[t], 0.f);
    ws[OFF_FDN + t] = fmaxf(fdn_hat[t], 0.f);
  }
  if (t < NS) {
    float s = 0.f;
    for (int w = 0; w < NW; ++w) s += w_err[t*NW + w];
    ws[OFF_QE + t] = -s;
  }
  __syncthreads();
  if (t == 0) {
    int uidx[NB];
    int cnt[NUPAD_MAX];
    int* ubus = (int*)(ws + OFF_UBUS);
    int* c2u  = (int*)(ws + OFF_C2U);
    int* cus  = (int*)(ws + OFF_CUS);
    int* cul  = (int*)(ws + OFF_CUL);
    for (int b = 0; b < NB; ++b) uidx[b] = -1;
    int nu = 0;
    for (int c = 0; c < NB; ++c) {
      const int b = bus[c];
      if (uidx[b] < 0) { uidx[b] = nu; ubus[nu] = b; nu++; }
      c2u[c] = uidx[b];
    }
    const int nuc = (nu <= NUC) ? NUC : 0;
    for (int u = nu; u < NUPAD_MAX; ++u) ubus[u] = 0;
    ((int*)(ws + OFF_NU))[0]  = nu;
    ((int*)(ws + OFF_NUP))[0] = (nu + 31) & ~31;
    ((int*)(ws + OFF_NUC))[0] = nuc;
    for (int u = 0; u < NUPAD_MAX; ++u) cnt[u] = 0;
    for (int c = 0; c < NB; ++c) cnt[c2u[c]]++;
    int acc = 0;
    for (int u = 0; u < nu; ++u) { cus[u] = acc; acc += cnt[u]; cnt[u] = cus[u]; }
    for (int u = nu; u <= NUPAD_MAX; ++u) cus[u] = acc;
    for (int c = 0; c < NB; ++c) cul[cnt[c2u[c]]++] = c;
  }
}

// ---------------------------------------------------------------- K2: gather HST, HSP, HWT
__global__ __launch_bounds__(512) void k_buildH(const float* __restrict__ PTDF, float* ws) {
  const int l = blockIdx.x;        // line 0..499
  const int t = threadIdx.x;
  const int NU  = ((const int*)(ws + OFF_NU))[0];
  const int NUCr = ((const int*)(ws + OFF_NUC))[0];
  const int* ubus = (const int*)(ws + OFF_UBUS);
  const int* busW = (const int*)(ws + OFF_BUSW);
  if (t < NUPAD_MAX) {
    const float val = (t < NU) ? PTDF[l*NB + ubus[t]] : 0.f;
    ws[OFF_HST + t*512 + l] = val;
    if (l == 0) {
      for (int ll = NLINE; ll < 512; ++ll) ws[OFF_HST + t*512 + ll] = 0.f;
    }
    if (NUCr > 0 && t < NUCr) {
      const int j = l >> 5, rg = l & 31;
      ws[OFF_HSP + ((j*NUC + t) << 5) + rg] = val;
      if (l == 0) {  // zero rows 500..511 (j=15, rg 20..31)
        for (int rr = NLINE; rr < 512; ++rr)
          ws[OFF_HSP + ((15*NUC + t) << 5) + (rr & 31)] = 0.f;
      }
    }
  } else if (t < NUPAD_MAX + NW) {
    const int w = t - NUPAD_MAX;
    ws[OFF_HWT + w*NLINE + l] = PTDF[l*NB + busW[w]];
  }
}

// ---------------------------------------------------------------- K3: B[e,f] = Hgl col_e . col_f
__global__ __launch_bounds__(320) void k_buildB(float* ws) {
  const int e = blockIdx.x;
  const int f = threadIdx.x;
  if (f >= NB) return;
  const int* c2u = (const int*)(ws + OFF_C2U);
  const float* __restrict__ re = ws + OFF_HST + c2u[e]*512;
  const float* __restrict__ rf = ws + OFF_HST + c2u[f]*512;
  float acc = 0.f;
  #pragma unroll 4
  for (int l = 0; l < NLINE; ++l)
    acc = fmaf(re[l], rf[l], acc);
  ws[OFF_B + e*NB + f] = acc;
}

// ---------------------------------------------------------------- K4: power iteration -> step
__global__ __launch_bounds__(1024) void k_power(float* ws) {
  __shared__ float v[NX];
  __shared__ float q3[NB];
  __shared__ float Bq3[3][NB];
  __shared__ float sE, sS;
  const int t = threadIdx.x;
  const float* __restrict__ B = ws + OFF_B;
  if (t < NX) v[t] = 1.0f / sqrtf(500.0f);
  __syncthreads();
  float s_last = 1.f;
  for (int it = 0; it < PITERS; ++it) {
    if (t < NG) q3[t] = v[t] - v[NG + t] - v[2*NG + t];
    else if (t < NB) q3[t] = v[t + 200];
    __syncthreads();
    if (t < 900) {
      const int c = t % NB, hh = t / NB;
      const int k0 = hh * 100;
      float a0 = 0.f, a1 = 0.f;
      for (int k = k0; k < k0 + 100; k += 2) {
        a0 = fmaf(B[k*NB + c],       q3[k],     a0);
        a1 = fmaf(B[(k+1)*NB + c],   q3[k+1],   a1);
      }
      Bq3[hh][c] = a0 + a1;
    } else if (t >= 960) {
      const int lane = t - 960;
      float e = 0.f;
      for (int k = lane; k < NB; k += 64) e += q3[k];
      for (int o = 32; o; o >>= 1) e += __shfl_down(e, o);
      if (lane == 0) sE = e;
    }
    __syncthreads();
    if (t < NX) {
      const float E = sE;
      const int ci = (t < NG) ? t : ((t < 2*NG) ? t - NG : ((t < NB) ? t - 2*NG : t - 200));
      const float bq = Bq3[0][ci] + Bq3[1][ci] + Bq3[2][ci];
      float nv;
      if (t < NG)        nv = v[t] + 2.f*bq + E;
      else if (t < 2*NG) nv = v[t] - 2.f*bq - E;
      else if (t < NB)   nv = -2.f*bq - E;
      else               nv = 2.f*bq + E;
      v[t] = nv;
    }
    __syncthreads();
    if (t < 64) {
      float p = 0.f;
      for (int k = t; k < NX; k += 64) p += v[k]*v[k];
      for (int o = 32; o; o >>= 1) p += __shfl_down(p, o);
      if (t == 0) sS = p;
    }
    __syncthreads();
    const float sn = sqrtf(sS);
    if (t < NX) v[t] /= sn;
    s_last = sn;
    __syncthreads();
  }
  if (t == 0) ws[OFF_STEP] = 0.9f / sqrtf(s_last);
}

// ---------------------------------------------------------------- K5: qC,qD per scenario
__global__ __launch_bounds__(512) void k_buildq(const float* __restrict__ w_err, float* ws) {
  const int s = blockIdx.x;
  const int t = threadIdx.x;
  __shared__ float wsh[NW];
  if (t < NW) wsh[t] = w_err[s*NW + t];
  __syncthreads();
  if (t < NLINE) {
    float wh = 0.f;
    #pragma unroll
    for (int w = 0; w < NW; ++w)
      wh = fmaf(wsh[w], ws[OFF_HWT + w*NLINE + t], wh);
    ws[OFF_QC + s*NLINE + t] = ws[OFF_FUP + t] - wh;
    ws[OFF_QD + s*NLINE + t] = ws[OFF_FDN + t] + wh;
  }
}

// ---------------------------------------------------------------- K6: PDHG, AGPR-pinned tile
// 512 threads: rg = t&31 (32 row-groups x 16 rows: l = rg+32j), cg = t>>5 (16 col-groups x 13)
// Tile: 208 floats/thread = 176 in AGPRs (asm-pinned, k<11) + 32 arch (k=11,12).
// 8 waves = 2/SIMD -> 256 unified regs/wave: 176 AGPR + ~80 arch. No spill possible for h.
__global__ __launch_bounds__(512, 2) void k_pdhg_reg(const float* __restrict__ ws,
                                                     float* __restrict__ out) {
  const int NUCr = ((const int*)(ws + OFF_NUC))[0];
  if (NUCr != NUC) return;          // bucket guard (uniform across grid)

  __shared__ float u_s[512], x_s[512], z_s[512];
  __shared__ float ts[NUC];
  __shared__ float fpart[8][512];
  __shared__ float yC[NLINE], yD[NLINE], qC[NLINE], qD[NLINE];
  __shared__ float yA[NG], yB[NG], qA[NG], qB[NG];
  __shared__ float sYE[1];
  __shared__ int c2u_s[NB], cus_s[NUPAD_MAX + 1], cul_s[NB];

  const int t = threadIdx.x;
  const int s = blockIdx.x;
  const int rg = t & 31, cg = t >> 5, w = t >> 6;
  const float step = ws[OFF_STEP];
  const float qE = ws[OFF_QE + s];

  // ---- init
  if (t < 512) { u_s[t] = 0.f; x_s[t] = 0.f; z_s[t] = 0.f; }
  if (t < NLINE) {
    yC[t] = 0.f; yD[t] = 0.f;
    qC[t] = ws[OFF_QC + s*NLINE + t];
    qD[t] = ws[OFF_QD + s*NLINE + t];
  }
  if (t < NG) { yA[t] = 0.f; yB[t] = 0.f; qA[t] = ws[OFF_RUP + t]; qB[t] = ws[OFF_RDN + t]; }
  if (t < NB) {
    c2u_s[t] = ((const int*)(ws + OFF_C2U))[t];
    cul_s[t] = ((const int*)(ws + OFF_CUL))[t];
  }
  if (t < NUPAD_MAX + 1) cus_s[t] = ((const int*)(ws + OFF_CUS))[t];
  if (t == 0) sYE[0] = 0.f;

  // ---- load tile: k<11 pinned to AGPRs, k=11,12 arch VGPRs
  float ha[16*NAG];      // AGPR-pinned (every def/use via asm "a")
  float hv[16][2];       // arch
  {
    const float* __restrict__ hp = ws + OFF_HSP;
    #pragma unroll
    for (int j = 0; j < 16; ++j) {
      #pragma unroll
      for (int k = 0; k < NAG; ++k) {
        const float v = hp[((j*NUC + cg*NC + k) << 5) + rg];
        asm("v_accvgpr_write_b32 %0, %1" : "=a"(ha[j*NAG + k]) : "v"(v));
      }
      hv[j][0] = hp[((j*NUC + cg*NC + 11) << 5) + rg];
      hv[j][1] = hp[((j*NUC + cg*NC + 12) << 5) + rg];
    }
  }
  __syncthreads();

  for (int it = 0; it < NITERS; ++it) {
    // ---- Phase A: ts[c] = sum_l Hs[l,c]*u[l]; rows reduced by 32-lane butterfly
    {
      float acc[NC];
      #pragma unroll
      for (int k = 0; k < NC; ++k) acc[k] = 0.f;
      #pragma unroll
      for (int j = 0; j < 16; ++j) {
        const float uj = u_s[rg + (j << 5)];
        #pragma unroll
        for (int k = 0; k < NAG; ++k) {
          float tp;
          asm("v_accvgpr_read_b32 %0, %1" : "=v"(tp) : "a"(ha[j*NAG + k]));
          acc[k] = fmaf(tp, uj, acc[k]);
        }
        acc[11] = fmaf(hv[j][0], uj, acc[11]);
        acc[12] = fmaf(hv[j][1], uj, acc[12]);
      }
      #pragma unroll
      for (int k = 0; k < NC; ++k) {
        float a = acc[k];
        a += __shfl_xor(a, 16); a += __shfl_xor(a, 8);
        a += __shfl_xor(a, 4);  a += __shfl_xor(a, 2); a += __shfl_xor(a, 1);
        acc[k] = a;
      }
      float wv = acc[0];
      #pragma unroll
      for (int k = 1; k < NC; ++k) wv = (rg == k) ? acc[k] : wv;
      if (rg < NC) ts[cg*NC + rg] = wv;
    }
    __syncthreads();

    // ---- Phase B: x-update
    if (t < NX) {
      const int cc = (t < NB) ? (t % NG) : (t - 200);
      const float tg = ts[c2u_s[cc]];
      const float yE = sYE[0];
      float yK;
      if (t < NG)        yK = yA[t] + tg + yE;
      else if (t < 2*NG) yK = yB[t - NG] - tg - yE;
      else if (t < NB)   yK = -tg - yE;
      else               yK = tg + yE;
      const float cj = (t < 2*NG) ? 0.f : CVIOL;
      const float xo = x_s[t];
      const float x1 = fmaxf(xo - step*(cj + yK), 0.f);
      z_s[t] = 2.f*x1 - xo;
      x_s[t] = x1;
    }
    __syncthreads();

    // ---- Phase C: in-thread busz for own NC cols, then f[l] partials
    {
      float b[NC];
      #pragma unroll
      for (int k = 0; k < NC; ++k) {
        const int c = cg*NC + k;
        float a = 0.f;
        const int k0 = cus_s[c], k1 = cus_s[c + 1];
        for (int kk = k0; kk < k1; ++kk) {
          const int comp = cul_s[kk];
          a += (comp < NG) ? (z_s[comp] - z_s[NG + comp] - z_s[2*NG + comp])
                           : z_s[200 + comp];
        }
        b[k] = a;
      }
      #pragma unroll
      for (int j = 0; j < 16; ++j) {
        float fp = 0.f;
        #pragma unroll
        for (int k = 0; k < NAG; ++k) {
          float tp;
          asm("v_accvgpr_read_b32 %0, %1" : "=v"(tp) : "a"(ha[j*NAG + k]));
          fp = fmaf(tp, b[k], fp);
        }
        fp = fmaf(hv[j][0], b[11], fp);
        fp = fmaf(hv[j][1], b[12], fp);
        fp += __shfl_xor(fp, 32);                 // combine cg pairs within wave
        if ((t & 32) == 0) fpart[w][rg + (j << 5)] = fp;
      }
    }
    __syncthreads();

    // ---- Phase D: y-updates + u for next iter; yA/yB folded in; E in wave 7
    if (t < NLINE) {
      float cv = 0.f;
      #pragma unroll
      for (int g = 0; g < 8; ++g) cv += fpart[g][t];
      const float cy = fmaxf(yC[t] + step*( cv - qC[t]), 0.f);
      const float dy = fmaxf(yD[t] + step*(-cv - qD[t]), 0.f);
      yC[t] = cy; yD[t] = dy; u_s[t] = cy - dy;
      if (t < NG)             yA[t]      = fmaxf(yA[t]      + step*(z_s[t]   - qA[t]),      0.f);
      else if (t < 2*NG)      yB[t - NG] = fmaxf(yB[t - NG] + step*(z_s[t]   - qB[t - NG]), 0.f);
    }
    if (t >= 448) {                     // wave 7: E = sum(sign * z)
      const int lane = t - 448;
      float e = 0.f;
      #pragma unroll
      for (int m = 0; m < 8; ++m) {
        const int idx = lane + (m << 6);
        const float zv = z_s[idx];
        e += (idx < NG || idx >= NB) ? zv : -zv;
      }
      e += __shfl_xor(e, 32); e += __shfl_xor(e, 16); e += __shfl_xor(e, 8);
      e += __shfl_xor(e, 4);  e += __shfl_xor(e, 2);  e += __shfl_xor(e, 1);
      if (t == 511) sYE[0] += step*(e - qE);
    }
    __syncthreads();
  }

  // ---- cost = CVIOL * sum(x[200:500])
  if (t < 64) {
    float p = 0.f;
    for (int k = 200 + t; k < NX; k += 64) p += x_s[k];
    for (int o = 32; o; o >>= 1) p += __shfl_down(p, o);
    if (t == 0) out[s] = CVIOL * p;
  }
}

// ---------------------------------------------------------------- K6fb: streaming fallback (NU > 208)
__global__ __launch_bounds__(1024) void k_pdhg_fb(const float* __restrict__ ws,
                                                  float* __restrict__ out) {
  const int NUCr = ((const int*)(ws + OFF_NUC))[0];
  if (NUCr != 0) return;
  const int NUPr = ((const int*)(ws + OFF_NUP))[0];

  __shared__ float u_s[512], x_s[512], z_s[512], cv_s[512];
  __shared__ float ts[NUPAD_MAX], busz[NUPAD_MAX];
  __shared__ float yC[NLINE], yD[NLINE], qC[NLINE], qD[NLINE];
  __shared__ float yA[NG], yB[NG], qA[NG], qB[NG];
  __shared__ float sE[1], sYE[1];
  __shared__ int c2u_s[NB], cus_s[NUPAD_MAX + 1], cul_s[NB];

  const int t = threadIdx.x;
  const int s = blockIdx.x;
  const float step = ws[OFF_STEP];
  const float qE = ws[OFF_QE + s];
  const float* __restrict__ HST = ws + OFF_HST;

  if (t < 512) { u_s[t] = 0.f; x_s[t] = 0.f; z_s[t] = 0.f; }
  if (t < NLINE) {
    yC[t] = 0.f; yD[t] = 0.f;
    qC[t] = ws[OFF_QC + s*NLINE + t];
    qD[t] = ws[OFF_QD + s*NLINE + t];
  }
  if (t < NG) { yA[t] = 0.f; yB[t] = 0.f; qA[t] = ws[OFF_RUP + t]; qB[t] = ws[OFF_RDN + t]; }
  if (t < NB) {
    c2u_s[t] = ((const int*)(ws + OFF_C2U))[t];
    cul_s[t] = ((const int*)(ws + OFF_CUL))[t];
  }
  if (t < NUPAD_MAX + 1) cus_s[t] = ((const int*)(ws + OFF_CUS))[t];
  if (t == 0) { sE[0] = 0.f; sYE[0] = 0.f; }
  __syncthreads();

  const int w = t >> 6, lane = t & 63;

  for (int it = 0; it < NITERS; ++it) {
    for (int c = w; c < NUPr; c += 16) {
      float a = 0.f;
      #pragma unroll
      for (int m = 0; m < 8; ++m) { const int l = lane + (m << 6); a = fmaf(HST[c*512 + l], u_s[l], a); }
      a += __shfl_xor(a, 32); a += __shfl_xor(a, 16); a += __shfl_xor(a, 8);
      a += __shfl_xor(a, 4);  a += __shfl_xor(a, 2);  a += __shfl_xor(a, 1);
      if (lane == 0) ts[c] = a;
    }
    __syncthreads();
    if (t < NX) {
      const int cc = (t < NB) ? (t % NG) : (t - 200);
      const float tg = ts[c2u_s[cc]];
      const float yE = sYE[0];
      float yK;
      if (t < NG)        yK = yA[t] + tg + yE;
      else if (t < 2*NG) yK = yB[t - NG] - tg - yE;
      else if (t < NB)   yK = -tg - yE;
      else               yK = tg + yE;
      const float cj = (t < 2*NG) ? 0.f : CVIOL;
      const float xo = x_s[t];
      const float x1 = fmaxf(xo - step*(cj + yK), 0.f);
      z_s[t] = 2.f*x1 - xo;
      x_s[t] = x1;
    }
    __syncthreads();
    if (t < NUPr) {
      float a = 0.f;
      const int k0 = cus_s[t], k1 = cus_s[t + 1];
      for (int k = k0; k < k1; ++k) {
        const int c = cul_s[k];
        a += (c < NG) ? (z_s[c] - z_s[NG + c] - z_s[2*NG + c]) : z_s[200 + c];
      }
      busz[t] = a;
    } else if (t >= 768 && t < 832) {
      const int ln = t - 768;
      float e = 0.f;
      for (int idx = ln; idx < NX; idx += 64) {
        const float zv = z_s[idx];
        e += (idx < NG || idx >= NB) ? zv : -zv;
      }
      e += __shfl_xor(e, 32); e += __shfl_xor(e, 16); e += __shfl_xor(e, 8);
      e += __shfl_xor(e, 4);  e += __shfl_xor(e, 2);  e += __shfl_xor(e, 1);
      if (ln == 0) sE[0] = e;
    }
    __syncthreads();
    if (t < 512) {
      float a = 0.f;
      for (int c = 0; c < NUPr; ++c) a = fmaf(HST[c*512 + t], busz[c], a);
      cv_s[t] = a;
    }
    __syncthreads();
    if (t < NLINE) {
      const float cv = cv_s[t];
      const float cy = fmaxf(yC[t] + step*( cv - qC[t]), 0.f);
      const float dy = fmaxf(yD[t] + step*(-cv - qD[t]), 0.f);
      yC[t] = cy; yD[t] = dy; u_s[t] = cy - dy;
    } else if (t >= 512 && t < 612) {
      const int g = t - 512;
      yA[g] = fmaxf(yA[g] + step*(z_s[g] - qA[g]), 0.f);
    } else if (t >= 612 && t < 712) {
      const int g = t - 612;
      yB[g] = fmaxf(yB[g] + step*(z_s[NG + g] - qB[g]), 0.f);
    } else if (t == 1023) {
      sYE[0] += step*(sE[0] - qE);
    }
    __syncthreads();
  }
  if (t < 64) {
    float p = 0.f;
    for (int k = 200 + t; k < NX; k += 64) p += x_s[k];
    for (int o = 32; o; o >>= 1) p += __shfl_down(p, o);
    if (t == 0) out[s] = CVIOL * p;
  }
}

extern "C" void kernel_launch(void* const* d_in, const int* in_sizes, int n_in,
                              void* d_out, int out_size, void* d_ws, size_t ws_size,
                              hipStream_t stream) {
  (void)in_sizes; (void)n_in; (void)out_size; (void)ws_size;
  const float* p_da      = (const float*)d_in[0];
  const float* r_up_hat  = (const float*)d_in[1];
  const float* r_dn_hat  = (const float*)d_in[2];
  const float* fup_hat   = (const float*)d_in[3];
  const float* fdn_hat   = (const float*)d_in[4];
  const float* w_err     = (const float*)d_in[5];
  const float* Pmax      = (const float*)d_in[6];
  const float* PTDF      = (const float*)d_in[7];
  const float* nG        = (const float*)d_in[8];
  const float* nL        = (const float*)d_in[9];
  const float* nW        = (const float*)d_in[10];
  float* ws  = (float*)d_ws;
  float* out = (float*)d_out;

  hipLaunchKernelGGL(k_pre,    dim3(1),   dim3(512),  0, stream,
                     p_da, r_up_hat, r_dn_hat, fup_hat, fdn_hat, w_err, Pmax, nG, nL, nW, ws);
  hipLaunchKernelGGL(k_buildH, dim3(500), dim3(512),  0, stream, PTDF, ws);
  hipLaunchKernelGGL(k_buildB, dim3(300), dim3(320),  0, stream, ws);
  hipLaunchKernelGGL(k_power,  dim3(1),   dim3(1024), 0, stream, ws);
  hipLaunchKernelGGL(k_buildq, dim3(128), dim3(512),  0, stream, w_err, ws);
  hipLaunchKernelGGL(k_pdhg_reg, dim3(128), dim3(512), 0, stream, ws, out);
  hipLaunchKernelGGL(k_pdhg_fb, dim3(128), dim3(1024), 0, stream, ws, out);
}

// Round 7
// 5683.582 us; speedup vs baseline: 1.1195x; 1.1195x over previous
//
#include <hip/hip_runtime.h>
#include <math.h>

#define NG 100
#define ND 200
#define NLINE 500
#define NB 300
#define NW 50
#define NS 128
#define NX 500
#define CVIOL 20000.0f
#define NITERS 600
#define PITERS 50
#define NUPAD_MAX 304

// k_pdhg_reg geometry: 512 threads, 16 col-groups x 13 cols, 32 row-groups,
// rows packed in pairs (l, l+32) as 2xbf16 per u32 -> 8 row-pair regs x 13 cols = 104 u32/thread
#define NC   13
#define NUC  208

// workspace layout (float offsets)
#define OFF_HSPB 0          // packed bf16 reg-load layout: 8*208*32 u32 = 53248
#define OFF_HST  114688     // 304*512 fp32
#define OFF_B    270336     // 300*300
#define OFF_HWT  360336     // 50*500
#define OFF_QC   385336     // 128*500
#define OFF_QD   449336     // 128*500
#define OFF_RUP  513336     // 100
#define OFF_RDN  513436     // 100
#define OFF_FUP  513536     // 500
#define OFF_FDN  514036     // 500
#define OFF_QE   514536     // 128
#define OFF_STEP 514664     // 1
#define OFF_NU   514665     // int
#define OFF_NUP  514666     // int
#define OFF_NUC  514667     // int (208 = reg kernel, 0 = fallback)
#define OFF_BUS  514668     // 300 ints
#define OFF_BUSW 514968     // 50 ints
#define OFF_UBUS 515018     // 304 ints
#define OFF_C2U  515322     // 300 ints
#define OFF_CUS  515622     // 305 ints
#define OFF_CUL  515927     // 300 ints

__device__ __forceinline__ float blo(unsigned int h) { return __uint_as_float(h << 16); }
__device__ __forceinline__ float bhi(unsigned int h) { return __uint_as_float(h & 0xffff0000u); }

// ---------------------------------------------------------------- K1: precompute + unique-bus build
__global__ __launch_bounds__(512) void k_pre(
    const float* __restrict__ p_da, const float* __restrict__ r_up_hat,
    const float* __restrict__ r_down_hat, const float* __restrict__ fup_hat,
    const float* __restrict__ fdn_hat, const float* __restrict__ w_err,
    const float* __restrict__ Pmax, const float* __restrict__ nG,
    const float* __restrict__ nL, const float* __restrict__ nW, float* ws) {
  const int t = threadIdx.x;
  int* bus  = (int*)(ws + OFF_BUS);
  int* busW = (int*)(ws + OFF_BUSW);
  if (t < NG) {
    int bf = 0;
    for (int b = 0; b < NB; ++b) if (nG[b*NG + t] > 0.5f) bf = b;
    bus[t] = bf;
    ws[OFF_RUP + t] = fmaxf(fminf(r_up_hat[t], Pmax[t] - p_da[t]), 0.f);
    ws[OFF_RDN + t] = fmaxf(fminf(r_down_hat[t], p_da[t]), 0.f);
  }
  if (t < ND) {
    int bf = 0;
    for (int b = 0; b < NB; ++b) if (nL[b*ND + t] > 0.5f) bf = b;
    bus[NG + t] = bf;
  }
  if (t < NW) {
    int bf = 0;
    for (int b = 0; b < NB; ++b) if (nW[b*NW + t] > 0.5f) bf = b;
    busW[t] = bf;
  }
  if (t < NLINE) {
    ws[OFF_FUP + t] = fmaxf(fup_hat[t], 0.f);
    ws[OFF_FDN + t] = fmaxf(fdn_hat[t], 0.f);
  }
  if (t < NS) {
    float s = 0.f;
    for (int w = 0; w < NW; ++w) s += w_err[t*NW + w];
    ws[OFF_QE + t] = -s;
  }
  __syncthreads();
  if (t == 0) {
    int uidx[NB];
    int cnt[NUPAD_MAX];
    int* ubus = (int*)(ws + OFF_UBUS);
    int* c2u  = (int*)(ws + OFF_C2U);
    int* cus  = (int*)(ws + OFF_CUS);
    int* cul  = (int*)(ws + OFF_CUL);
    for (int b = 0; b < NB; ++b) uidx[b] = -1;
    int nu = 0;
    for (int c = 0; c < NB; ++c) {
      const int b = bus[c];
      if (uidx[b] < 0) { uidx[b] = nu; ubus[nu] = b; nu++; }
      c2u[c] = uidx[b];
    }
    const int nuc = (nu <= NUC) ? NUC : 0;
    for (int u = nu; u < NUPAD_MAX; ++u) ubus[u] = 0;
    ((int*)(ws + OFF_NU))[0]  = nu;
    ((int*)(ws + OFF_NUP))[0] = (nu + 31) & ~31;
    ((int*)(ws + OFF_NUC))[0] = nuc;
    for (int u = 0; u < NUPAD_MAX; ++u) cnt[u] = 0;
    for (int c = 0; c < NB; ++c) cnt[c2u[c]]++;
    int acc = 0;
    for (int u = 0; u < nu; ++u) { cus[u] = acc; acc += cnt[u]; cnt[u] = cus[u]; }
    for (int u = nu; u <= NUPAD_MAX; ++u) cus[u] = acc;
    for (int c = 0; c < NB; ++c) cul[cnt[c2u[c]]++] = c;
  }
}

// ---------------------------------------------------------------- K2: gather HST (fp32) + HSPB (packed bf16)
__global__ __launch_bounds__(512) void k_buildH(const float* __restrict__ PTDF, float* ws) {
  const int l = blockIdx.x;        // line 0..499
  const int t = threadIdx.x;
  const int NU   = ((const int*)(ws + OFF_NU))[0];
  const int NUCr = ((const int*)(ws + OFF_NUC))[0];
  const int* ubus = (const int*)(ws + OFF_UBUS);
  const int* busW = (const int*)(ws + OFF_BUSW);
  unsigned short* hb = (unsigned short*)(ws + OFF_HSPB);
  if (t < NUPAD_MAX) {
    const float val = (t < NU) ? PTDF[l*NB + ubus[t]] : 0.f;
    ws[OFF_HST + t*512 + l] = val;
    if (l == 0) {
      for (int ll = NLINE; ll < 512; ++ll) ws[OFF_HST + t*512 + ll] = 0.f;
    }
    if (NUCr > 0 && t < NUCr) {
      const int jp = l >> 6, half = (l >> 5) & 1, rg = l & 31;
      const unsigned int u = __float_as_uint(val);
      const unsigned short bv = (unsigned short)((u + 0x7fffu + ((u >> 16) & 1u)) >> 16);  // RNE bf16
      hb[((((jp*NUC + t) << 5) + rg) << 1) + half] = bv;
      if (l == 0) {  // zero rows 500..511: jp=7, half=1, rg=20..31
        for (int rr = 20; rr < 32; ++rr)
          hb[((((7*NUC + t) << 5) + rr) << 1) + 1] = 0;
      }
    }
  } else if (t < NUPAD_MAX + NW) {
    const int w = t - NUPAD_MAX;
    ws[OFF_HWT + w*NLINE + l] = PTDF[l*NB + busW[w]];
  }
}

// ---------------------------------------------------------------- K3: B[e,f] = Hgl col_e . col_f (fp32)
__global__ __launch_bounds__(320) void k_buildB(float* ws) {
  const int e = blockIdx.x;
  const int f = threadIdx.x;
  if (f >= NB) return;
  const int* c2u = (const int*)(ws + OFF_C2U);
  const float* __restrict__ re = ws + OFF_HST + c2u[e]*512;
  const float* __restrict__ rf = ws + OFF_HST + c2u[f]*512;
  float acc = 0.f;
  #pragma unroll 4
  for (int l = 0; l < NLINE; ++l)
    acc = fmaf(re[l], rf[l], acc);
  ws[OFF_B + e*NB + f] = acc;
}

// ---------------------------------------------------------------- K4: power iteration -> step
__global__ __launch_bounds__(1024) void k_power(float* ws) {
  __shared__ float v[NX];
  __shared__ float q3[NB];
  __shared__ float Bq3[3][NB];
  __shared__ float sE, sS;
  const int t = threadIdx.x;
  const float* __restrict__ B = ws + OFF_B;
  if (t < NX) v[t] = 1.0f / sqrtf(500.0f);
  __syncthreads();
  float s_last = 1.f;
  for (int it = 0; it < PITERS; ++it) {
    if (t < NG) q3[t] = v[t] - v[NG + t] - v[2*NG + t];
    else if (t < NB) q3[t] = v[t + 200];
    __syncthreads();
    if (t < 900) {
      const int c = t % NB, hh = t / NB;
      const int k0 = hh * 100;
      float a0 = 0.f, a1 = 0.f;
      for (int k = k0; k < k0 + 100; k += 2) {
        a0 = fmaf(B[k*NB + c],       q3[k],     a0);
        a1 = fmaf(B[(k+1)*NB + c],   q3[k+1],   a1);
      }
      Bq3[hh][c] = a0 + a1;
    } else if (t >= 960) {
      const int lane = t - 960;
      float e = 0.f;
      for (int k = lane; k < NB; k += 64) e += q3[k];
      for (int o = 32; o; o >>= 1) e += __shfl_down(e, o);
      if (lane == 0) sE = e;
    }
    __syncthreads();
    if (t < NX) {
      const float E = sE;
      const int ci = (t < NG) ? t : ((t < 2*NG) ? t - NG : ((t < NB) ? t - 2*NG : t - 200));
      const float bq = Bq3[0][ci] + Bq3[1][ci] + Bq3[2][ci];
      float nv;
      if (t < NG)        nv = v[t] + 2.f*bq + E;
      else if (t < 2*NG) nv = v[t] - 2.f*bq - E;
      else if (t < NB)   nv = -2.f*bq - E;
      else               nv = 2.f*bq + E;
      v[t] = nv;
    }
    __syncthreads();
    if (t < 64) {
      float p = 0.f;
      for (int k = t; k < NX; k += 64) p += v[k]*v[k];
      for (int o = 32; o; o >>= 1) p += __shfl_down(p, o);
      if (t == 0) sS = p;
    }
    __syncthreads();
    const float sn = sqrtf(sS);
    if (t < NX) v[t] /= sn;
    s_last = sn;
    __syncthreads();
  }
  if (t == 0) ws[OFF_STEP] = 0.9f / sqrtf(s_last);
}

// ---------------------------------------------------------------- K5: qC,qD per scenario
__global__ __launch_bounds__(512) void k_buildq(const float* __restrict__ w_err, float* ws) {
  const int s = blockIdx.x;
  const int t = threadIdx.x;
  __shared__ float wsh[NW];
  if (t < NW) wsh[t] = w_err[s*NW + t];
  __syncthreads();
  if (t < NLINE) {
    float wh = 0.f;
    #pragma unroll
    for (int w = 0; w < NW; ++w)
      wh = fmaf(wsh[w], ws[OFF_HWT + w*NLINE + t], wh);
    ws[OFF_QC + s*NLINE + t] = ws[OFF_FUP + t] - wh;
    ws[OFF_QD + s*NLINE + t] = ws[OFF_FDN + t] + wh;
  }
}

// ---------------------------------------------------------------- macro machinery for named registers
#define ROWK(M,jp) M(jp,0) M(jp,1) M(jp,2) M(jp,3) M(jp,4) M(jp,5) M(jp,6) \
                   M(jp,7) M(jp,8) M(jp,9) M(jp,10) M(jp,11) M(jp,12)
#define JPLIST(M) M(0) M(1) M(2) M(3) M(4) M(5) M(6) M(7)
#define KLIST(M)  M(0) M(1) M(2) M(3) M(4) M(5) M(6) M(7) M(8) M(9) M(10) M(11) M(12)
#define KLIST1(M) M(1) M(2) M(3) M(4) M(5) M(6) M(7) M(8) M(9) M(10) M(11) M(12)

#define DECLH(jp,k) unsigned int h##jp##_##k;
#define DECLROW(jp) ROWK(DECLH,jp)
#define LDH(jp,k)   h##jp##_##k = hpu[((((jp)*NUC) + cbase + (k)) << 5) + rg];
#define LDROW(jp)   ROWK(LDH,jp)
#define ACCD(k)     float acc##k = 0.f;
#define FMAA(jp,k)  acc##k = fmaf(blo(h##jp##_##k), u0, fmaf(bhi(h##jp##_##k), u1, acc##k));
#define PHA(jp)     { const float u0 = u_s[rg + ((jp) << 6)]; \
                      const float u1 = u_s[rg + ((jp) << 6) + 32]; ROWK(FMAA,jp) }
#define BFLY(k)     acc##k += __shfl_xor(acc##k, 16); acc##k += __shfl_xor(acc##k, 8); \
                    acc##k += __shfl_xor(acc##k, 4);  acc##k += __shfl_xor(acc##k, 2); \
                    acc##k += __shfl_xor(acc##k, 1);
#define SELK(k)     wv = (rg == (k)) ? acc##k : wv;
#define DECB(k)     float b##k = 0.f; { const int c = cbase + (k); \
                      const int ke = cus_s[c + 1]; \
                      for (int kk = cus_s[c]; kk < ke; ++kk) { const int comp = cul_s[kk]; \
                        b##k += (comp < NG) ? (z_s[comp] - z_s[NG + comp] - z_s[2*NG + comp]) \
                                            : z_s[200 + comp]; } }
#define FMAC(jp,k)  fp0 = fmaf(blo(h##jp##_##k), b##k, fp0); \
                    fp1 = fmaf(bhi(h##jp##_##k), b##k, fp1);
#define PHC(jp)     { float fp0 = 0.f, fp1 = 0.f; ROWK(FMAC,jp) \
                      fp0 += __shfl_xor(fp0, 32); fp1 += __shfl_xor(fp1, 32); \
                      if ((t & 32) == 0) { fpart[w][rg + ((jp) << 6)]      = fp0; \
                                           fpart[w][rg + ((jp) << 6) + 32] = fp1; } }

// ---------------------------------------------------------------- K6: PDHG, bf16-packed named-register tile
// 512 threads: rg = t&31, cg = t>>5. Rows l = rg + 32j (j<16) held as 8 row-pairs (l, l+32)
// packed 2xbf16/u32. 104 named u32 regs/thread; launch_bounds(512,2) -> 256-reg budget.
__global__ __launch_bounds__(512, 2) void k_pdhg_reg(const float* __restrict__ ws,
                                                     float* __restrict__ out) {
  const int NUCr = ((const int*)(ws + OFF_NUC))[0];
  if (NUCr != NUC) return;          // bucket guard (uniform across grid)

  __shared__ float u_s[512], x_s[512], z_s[512];
  __shared__ float ts[NUC];
  __shared__ float fpart[8][512];
  __shared__ float yC[NLINE], yD[NLINE], qC[NLINE], qD[NLINE];
  __shared__ float yA[NG], yB[NG], qA[NG], qB[NG];
  __shared__ float sYE[1];
  __shared__ int c2u_s[NB], cus_s[NUPAD_MAX + 1], cul_s[NB];

  const int t = threadIdx.x;
  const int s = blockIdx.x;
  const int rg = t & 31, cg = t >> 5, w = t >> 6;
  const int cbase = cg * NC;
  const float step = ws[OFF_STEP];
  const float qE = ws[OFF_QE + s];

  // ---- init
  if (t < 512) { u_s[t] = 0.f; x_s[t] = 0.f; z_s[t] = 0.f; }
  if (t < NLINE) {
    yC[t] = 0.f; yD[t] = 0.f;
    qC[t] = ws[OFF_QC + s*NLINE + t];
    qD[t] = ws[OFF_QD + s*NLINE + t];
  }
  if (t < NG) { yA[t] = 0.f; yB[t] = 0.f; qA[t] = ws[OFF_RUP + t]; qB[t] = ws[OFF_RDN + t]; }
  if (t < NB) {
    c2u_s[t] = ((const int*)(ws + OFF_C2U))[t];
    cul_s[t] = ((const int*)(ws + OFF_CUL))[t];
  }
  if (t < NUPAD_MAX + 1) cus_s[t] = ((const int*)(ws + OFF_CUS))[t];
  if (t == 0) sYE[0] = 0.f;

  // ---- load packed tile into 104 named registers (coalesced over rg)
  JPLIST(DECLROW)
  {
    const unsigned int* __restrict__ hpu = (const unsigned int*)(ws + OFF_HSPB);
    JPLIST(LDROW)
  }
  __syncthreads();

  for (int it = 0; it < NITERS; ++it) {
    // ---- Phase A: ts[c] = sum_l Hs[l,c]*u[l]; rows reduced by 32-lane butterfly
    {
      KLIST(ACCD)
      JPLIST(PHA)
      KLIST(BFLY)
      float wv = acc0;
      KLIST1(SELK)
      if (rg < NC) ts[cbase + rg] = wv;
    }
    __syncthreads();

    // ---- Phase B: x-update
    if (t < NX) {
      const int cc = (t < NB) ? (t % NG) : (t - 200);
      const float tg = ts[c2u_s[cc]];
      const float yE = sYE[0];
      float yK;
      if (t < NG)        yK = yA[t] + tg + yE;
      else if (t < 2*NG) yK = yB[t - NG] - tg - yE;
      else if (t < NB)   yK = -tg - yE;
      else               yK = tg + yE;
      const float cj = (t < 2*NG) ? 0.f : CVIOL;
      const float xo = x_s[t];
      const float x1 = fmaxf(xo - step*(cj + yK), 0.f);
      z_s[t] = 2.f*x1 - xo;
      x_s[t] = x1;
    }
    __syncthreads();

    // ---- Phase C: in-thread busz for own 13 cols, then f[l] partials
    {
      KLIST(DECB)
      JPLIST(PHC)
    }
    __syncthreads();

    // ---- Phase D: y-updates + u for next iter; yA/yB folded in; E in wave 7
    if (t < NLINE) {
      float cv = 0.f;
      #pragma unroll
      for (int g = 0; g < 8; ++g) cv += fpart[g][t];
      const float cy = fmaxf(yC[t] + step*( cv - qC[t]), 0.f);
      const float dy = fmaxf(yD[t] + step*(-cv - qD[t]), 0.f);
      yC[t] = cy; yD[t] = dy; u_s[t] = cy - dy;
      if (t < NG)             yA[t]      = fmaxf(yA[t]      + step*(z_s[t]   - qA[t]),      0.f);
      else if (t < 2*NG)      yB[t - NG] = fmaxf(yB[t - NG] + step*(z_s[t]   - qB[t - NG]), 0.f);
    }
    if (t >= 448) {                     // wave 7: E = sum(sign * z)
      const int lane = t - 448;
      float e = 0.f;
      #pragma unroll
      for (int m = 0; m < 8; ++m) {
        const int idx = lane + (m << 6);
        const float zv = z_s[idx];
        e += (idx < NG || idx >= NB) ? zv : -zv;
      }
      e += __shfl_xor(e, 32); e += __shfl_xor(e, 16); e += __shfl_xor(e, 8);
      e += __shfl_xor(e, 4);  e += __shfl_xor(e, 2);  e += __shfl_xor(e, 1);
      if (t == 511) sYE[0] += step*(e - qE);
    }
    __syncthreads();
  }

  // ---- cost = CVIOL * sum(x[200:500])
  if (t < 64) {
    float p = 0.f;
    for (int k = 200 + t; k < NX; k += 64) p += x_s[k];
    for (int o = 32; o; o >>= 1) p += __shfl_down(p, o);
    if (t == 0) out[s] = CVIOL * p;
  }
}

// ---------------------------------------------------------------- K6fb: streaming fallback (NU > 208)
__global__ __launch_bounds__(1024) void k_pdhg_fb(const float* __restrict__ ws,
                                                  float* __restrict__ out) {
  const int NUCr = ((const int*)(ws + OFF_NUC))[0];
  if (NUCr != 0) return;
  const int NUPr = ((const int*)(ws + OFF_NUP))[0];

  __shared__ float u_s[512], x_s[512], z_s[512], cv_s[512];
  __shared__ float ts[NUPAD_MAX], busz[NUPAD_MAX];
  __shared__ float yC[NLINE], yD[NLINE], qC[NLINE], qD[NLINE];
  __shared__ float yA[NG], yB[NG], qA[NG], qB[NG];
  __shared__ float sE[1], sYE[1];
  __shared__ int c2u_s[NB], cus_s[NUPAD_MAX + 1], cul_s[NB];

  const int t = threadIdx.x;
  const int s = blockIdx.x;
  const float step = ws[OFF_STEP];
  const float qE = ws[OFF_QE + s];
  const float* __restrict__ HST = ws + OFF_HST;

  if (t < 512) { u_s[t] = 0.f; x_s[t] = 0.f; z_s[t] = 0.f; }
  if (t < NLINE) {
    yC[t] = 0.f; yD[t] = 0.f;
    qC[t] = ws[OFF_QC + s*NLINE + t];
    qD[t] = ws[OFF_QD + s*NLINE + t];
  }
  if (t < NG) { yA[t] = 0.f; yB[t] = 0.f; qA[t] = ws[OFF_RUP + t]; qB[t] = ws[OFF_RDN + t]; }
  if (t < NB) {
    c2u_s[t] = ((const int*)(ws + OFF_C2U))[t];
    cul_s[t] = ((const int*)(ws + OFF_CUL))[t];
  }
  if (t < NUPAD_MAX + 1) cus_s[t] = ((const int*)(ws + OFF_CUS))[t];
  if (t == 0) { sE[0] = 0.f; sYE[0] = 0.f; }
  __syncthreads();

  const int w = t >> 6, lane = t & 63;

  for (int it = 0; it < NITERS; ++it) {
    for (int c = w; c < NUPr; c += 16) {
      float a = 0.f;
      #pragma unroll
      for (int m = 0; m < 8; ++m) { const int l = lane + (m << 6); a = fmaf(HST[c*512 + l], u_s[l], a); }
      a += __shfl_xor(a, 32); a += __shfl_xor(a, 16); a += __shfl_xor(a, 8);
      a += __shfl_xor(a, 4);  a += __shfl_xor(a, 2);  a += __shfl_xor(a, 1);
      if (lane == 0) ts[c] = a;
    }
    __syncthreads();
    if (t < NX) {
      const int cc = (t < NB) ? (t % NG) : (t - 200);
      const float tg = ts[c2u_s[cc]];
      const float yE = sYE[0];
      float yK;
      if (t < NG)        yK = yA[t] + tg + yE;
      else if (t < 2*NG) yK = yB[t - NG] - tg - yE;
      else if (t < NB)   yK = -tg - yE;
      else               yK = tg + yE;
      const float cj = (t < 2*NG) ? 0.f : CVIOL;
      const float xo = x_s[t];
      const float x1 = fmaxf(xo - step*(cj + yK), 0.f);
      z_s[t] = 2.f*x1 - xo;
      x_s[t] = x1;
    }
    __syncthreads();
    if (t < NUPr) {
      float a = 0.f;
      const int k0 = cus_s[t], k1 = cus_s[t + 1];
      for (int k = k0; k < k1; ++k) {
        const int c = cul_s[k];
        a += (c < NG) ? (z_s[c] - z_s[NG + c] - z_s[2*NG + c]) : z_s[200 + c];
      }
      busz[t] = a;
    } else if (t >= 768 && t < 832) {
      const int ln = t - 768;
      float e = 0.f;
      for (int idx = ln; idx < NX; idx += 64) {
        const float zv = z_s[idx];
        e += (idx < NG || idx >= NB) ? zv : -zv;
      }
      e += __shfl_xor(e, 32); e += __shfl_xor(e, 16); e += __shfl_xor(e, 8);
      e += __shfl_xor(e, 4);  e += __shfl_xor(e, 2);  e += __shfl_xor(e, 1);
      if (ln == 0) sE[0] = e;
    }
    __syncthreads();
    if (t < 512) {
      float a = 0.f;
      for (int c = 0; c < NUPr; ++c) a = fmaf(HST[c*512 + t], busz[c], a);
      cv_s[t] = a;
    }
    __syncthreads();
    if (t < NLINE) {
      const float cv = cv_s[t];
      const float cy = fmaxf(yC[t] + step*( cv - qC[t]), 0.f);
      const float dy = fmaxf(yD[t] + step*(-cv - qD[t]), 0.f);
      yC[t] = cy; yD[t] = dy; u_s[t] = cy - dy;
    } else if (t >= 512 && t < 612) {
      const int g = t - 512;
      yA[g] = fmaxf(yA[g] + step*(z_s[g] - qA[g]), 0.f);
    } else if (t >= 612 && t < 712) {
      const int g = t - 612;
      yB[g] = fmaxf(yB[g] + step*(z_s[NG + g] - qB[g]), 0.f);
    } else if (t == 1023) {
      sYE[0] += step*(sE[0] - qE);
    }
    __syncthreads();
  }
  if (t < 64) {
    float p = 0.f;
    for (int k = 200 + t; k < NX; k += 64) p += x_s[k];
    for (int o = 32; o; o >>= 1) p += __shfl_down(p, o);
    if (t == 0) out[s] = CVIOL * p;
  }
}

extern "C" void kernel_launch(void* const* d_in, const int* in_sizes, int n_in,
                              void* d_out, int out_size, void* d_ws, size_t ws_size,
                              hipStream_t stream) {
  (void)in_sizes; (void)n_in; (void)out_size; (void)ws_size;
  const float* p_da      = (const float*)d_in[0];
  const float* r_up_hat  = (const float*)d_in[1];
  const float* r_dn_hat  = (const float*)d_in[2];
  const float* fup_hat   = (const float*)d_in[3];
  const float* fdn_hat   = (const float*)d_in[4];
  const float* w_err     = (const float*)d_in[5];
  const float* Pmax      = (const float*)d_in[6];
  const float* PTDF      = (const float*)d_in[7];
  const float* nG        = (const float*)d_in[8];
  const float* nL        = (const float*)d_in[9];
  const float* nW        = (const float*)d_in[10];
  float* ws  = (float*)d_ws;
  float* out = (float*)d_out;

  hipLaunchKernelGGL(k_pre,    dim3(1),   dim3(512),  0, stream,
                     p_da, r_up_hat, r_dn_hat, fup_hat, fdn_hat, w_err, Pmax, nG, nL, nW, ws);
  hipLaunchKernelGGL(k_buildH, dim3(500), dim3(512),  0, stream, PTDF, ws);
  hipLaunchKernelGGL(k_buildB, dim3(300), dim3(320),  0, stream, ws);
  hipLaunchKernelGGL(k_power,  dim3(1),   dim3(1024), 0, stream, ws);
  hipLaunchKernelGGL(k_buildq, dim3(128), dim3(512),  0, stream, w_err, ws);
  hipLaunchKernelGGL(k_pdhg_reg, dim3(128), dim3(512), 0, stream, ws, out);
  hipLaunchKernelGGL(k_pdhg_fb, dim3(128), dim3(1024), 0, stream, ws, out);
}

// Round 8
// 5678.725 us; speedup vs baseline: 1.1205x; 1.0009x over previous
//
#include <hip/hip_runtime.h>
#include <math.h>

#define NG 100
#define ND 200
#define NLINE 500
#define NB 300
#define NW 50
#define NS 128
#define NX 500
#define CVIOL 20000.0f
#define NITERS 600
#define PITERS 50
#define NUPAD_MAX 304

// k_pdhg_reg geometry: 512 threads, 16 col-groups x 13 cols, 32 row-groups,
// rows packed in pairs (l, l+32) as 2xbf16 per u32 -> 8 row-pair regs x 13 cols = 104 u32/thread
#define NC   13
#define NUC  208

// workspace layout (float offsets)
#define OFF_HSPB 0          // packed bf16 reg-load layout: 8*208*32 u32 = 53248
#define OFF_HST  114688     // 304*512 fp32
#define OFF_B    270336     // 300*300
#define OFF_HWT  360336     // 50*500
#define OFF_QC   385336     // 128*500
#define OFF_QD   449336     // 128*500
#define OFF_RUP  513336     // 100
#define OFF_RDN  513436     // 100
#define OFF_FUP  513536     // 500
#define OFF_FDN  514036     // 500
#define OFF_QE   514536     // 128
#define OFF_STEP 514664     // 1
#define OFF_NU   514665     // int
#define OFF_NUP  514666     // int
#define OFF_NUC  514667     // int (208 = reg kernel, 0 = fallback)
#define OFF_BUS  514668     // 300 ints
#define OFF_BUSW 514968     // 50 ints
#define OFF_UBUS 515018     // 304 ints
#define OFF_C2U  515322     // 300 ints
#define OFF_CUS  515622     // 305 ints
#define OFF_CUL  515927     // 300 ints

__device__ __forceinline__ float blo(unsigned int h) { return __uint_as_float(h << 16); }
__device__ __forceinline__ float bhi(unsigned int h) { return __uint_as_float(h & 0xffff0000u); }

// ---------------------------------------------------------------- K1: precompute + unique-bus build
__global__ __launch_bounds__(512) void k_pre(
    const float* __restrict__ p_da, const float* __restrict__ r_up_hat,
    const float* __restrict__ r_down_hat, const float* __restrict__ fup_hat,
    const float* __restrict__ fdn_hat, const float* __restrict__ w_err,
    const float* __restrict__ Pmax, const float* __restrict__ nG,
    const float* __restrict__ nL, const float* __restrict__ nW, float* ws) {
  const int t = threadIdx.x;
  int* bus  = (int*)(ws + OFF_BUS);
  int* busW = (int*)(ws + OFF_BUSW);
  if (t < NG) {
    int bf = 0;
    for (int b = 0; b < NB; ++b) if (nG[b*NG + t] > 0.5f) bf = b;
    bus[t] = bf;
    ws[OFF_RUP + t] = fmaxf(fminf(r_up_hat[t], Pmax[t] - p_da[t]), 0.f);
    ws[OFF_RDN + t] = fmaxf(fminf(r_down_hat[t], p_da[t]), 0.f);
  }
  if (t < ND) {
    int bf = 0;
    for (int b = 0; b < NB; ++b) if (nL[b*ND + t] > 0.5f) bf = b;
    bus[NG + t] = bf;
  }
  if (t < NW) {
    int bf = 0;
    for (int b = 0; b < NB; ++b) if (nW[b*NW + t] > 0.5f) bf = b;
    busW[t] = bf;
  }
  if (t < NLINE) {
    ws[OFF_FUP + t] = fmaxf(fup_hat[t], 0.f);
    ws[OFF_FDN + t] = fmaxf(fdn_hat[t], 0.f);
  }
  if (t < NS) {
    float s = 0.f;
    for (int w = 0; w < NW; ++w) s += w_err[t*NW + w];
    ws[OFF_QE + t] = -s;
  }
  __syncthreads();
  if (t == 0) {
    int uidx[NB];
    int cnt[NUPAD_MAX];
    int* ubus = (int*)(ws + OFF_UBUS);
    int* c2u  = (int*)(ws + OFF_C2U);
    int* cus  = (int*)(ws + OFF_CUS);
    int* cul  = (int*)(ws + OFF_CUL);
    for (int b = 0; b < NB; ++b) uidx[b] = -1;
    int nu = 0;
    for (int c = 0; c < NB; ++c) {
      const int b = bus[c];
      if (uidx[b] < 0) { uidx[b] = nu; ubus[nu] = b; nu++; }
      c2u[c] = uidx[b];
    }
    const int nuc = (nu <= NUC) ? NUC : 0;
    for (int u = nu; u < NUPAD_MAX; ++u) ubus[u] = 0;
    ((int*)(ws + OFF_NU))[0]  = nu;
    ((int*)(ws + OFF_NUP))[0] = (nu + 31) & ~31;
    ((int*)(ws + OFF_NUC))[0] = nuc;
    for (int u = 0; u < NUPAD_MAX; ++u) cnt[u] = 0;
    for (int c = 0; c < NB; ++c) cnt[c2u[c]]++;
    int acc = 0;
    for (int u = 0; u < nu; ++u) { cus[u] = acc; acc += cnt[u]; cnt[u] = cus[u]; }
    for (int u = nu; u <= NUPAD_MAX; ++u) cus[u] = acc;
    for (int c = 0; c < NB; ++c) cul[cnt[c2u[c]]++] = c;
  }
}

// ---------------------------------------------------------------- K2: gather HST (fp32) + HSPB (packed bf16)
__global__ __launch_bounds__(512) void k_buildH(const float* __restrict__ PTDF, float* ws) {
  const int l = blockIdx.x;        // line 0..499
  const int t = threadIdx.x;
  const int NU   = ((const int*)(ws + OFF_NU))[0];
  const int NUCr = ((const int*)(ws + OFF_NUC))[0];
  const int* ubus = (const int*)(ws + OFF_UBUS);
  const int* busW = (const int*)(ws + OFF_BUSW);
  unsigned short* hb = (unsigned short*)(ws + OFF_HSPB);
  if (t < NUPAD_MAX) {
    const float val = (t < NU) ? PTDF[l*NB + ubus[t]] : 0.f;
    ws[OFF_HST + t*512 + l] = val;
    if (l == 0) {
      for (int ll = NLINE; ll < 512; ++ll) ws[OFF_HST + t*512 + ll] = 0.f;
    }
    if (NUCr > 0 && t < NUCr) {
      const int jp = l >> 6, half = (l >> 5) & 1, rg = l & 31;
      const unsigned int u = __float_as_uint(val);
      const unsigned short bv = (unsigned short)((u + 0x7fffu + ((u >> 16) & 1u)) >> 16);  // RNE bf16
      hb[((((jp*NUC + t) << 5) + rg) << 1) + half] = bv;
      if (l == 0) {  // zero rows 500..511: jp=7, half=1, rg=20..31
        for (int rr = 20; rr < 32; ++rr)
          hb[((((7*NUC + t) << 5) + rr) << 1) + 1] = 0;
      }
    }
  } else if (t < NUPAD_MAX + NW) {
    const int w = t - NUPAD_MAX;
    ws[OFF_HWT + w*NLINE + l] = PTDF[l*NB + busW[w]];
  }
}

// ---------------------------------------------------------------- K3: B[e,f] = Hgl col_e . col_f (fp32)
__global__ __launch_bounds__(320) void k_buildB(float* ws) {
  const int e = blockIdx.x;
  const int f = threadIdx.x;
  if (f >= NB) return;
  const int* c2u = (const int*)(ws + OFF_C2U);
  const float* __restrict__ re = ws + OFF_HST + c2u[e]*512;
  const float* __restrict__ rf = ws + OFF_HST + c2u[f]*512;
  float acc = 0.f;
  #pragma unroll 4
  for (int l = 0; l < NLINE; ++l)
    acc = fmaf(re[l], rf[l], acc);
  ws[OFF_B + e*NB + f] = acc;
}

// ---------------------------------------------------------------- K4: power iteration -> step
__global__ __launch_bounds__(1024) void k_power(float* ws) {
  __shared__ float v[NX];
  __shared__ float q3[NB];
  __shared__ float Bq3[3][NB];
  __shared__ float sE, sS;
  const int t = threadIdx.x;
  const float* __restrict__ B = ws + OFF_B;
  if (t < NX) v[t] = 1.0f / sqrtf(500.0f);
  __syncthreads();
  float s_last = 1.f;
  for (int it = 0; it < PITERS; ++it) {
    if (t < NG) q3[t] = v[t] - v[NG + t] - v[2*NG + t];
    else if (t < NB) q3[t] = v[t + 200];
    __syncthreads();
    if (t < 900) {
      const int c = t % NB, hh = t / NB;
      const int k0 = hh * 100;
      float a0 = 0.f, a1 = 0.f;
      for (int k = k0; k < k0 + 100; k += 2) {
        a0 = fmaf(B[k*NB + c],       q3[k],     a0);
        a1 = fmaf(B[(k+1)*NB + c],   q3[k+1],   a1);
      }
      Bq3[hh][c] = a0 + a1;
    } else if (t >= 960) {
      const int lane = t - 960;
      float e = 0.f;
      for (int k = lane; k < NB; k += 64) e += q3[k];
      for (int o = 32; o; o >>= 1) e += __shfl_down(e, o);
      if (lane == 0) sE = e;
    }
    __syncthreads();
    if (t < NX) {
      const float E = sE;
      const int ci = (t < NG) ? t : ((t < 2*NG) ? t - NG : ((t < NB) ? t - 2*NG : t - 200));
      const float bq = Bq3[0][ci] + Bq3[1][ci] + Bq3[2][ci];
      float nv;
      if (t < NG)        nv = v[t] + 2.f*bq + E;
      else if (t < 2*NG) nv = v[t] - 2.f*bq - E;
      else if (t < NB)   nv = -2.f*bq - E;
      else               nv = 2.f*bq + E;
      v[t] = nv;
    }
    __syncthreads();
    if (t < 64) {
      float p = 0.f;
      for (int k = t; k < NX; k += 64) p += v[k]*v[k];
      for (int o = 32; o; o >>= 1) p += __shfl_down(p, o);
      if (t == 0) sS = p;
    }
    __syncthreads();
    const float sn = sqrtf(sS);
    if (t < NX) v[t] /= sn;
    s_last = sn;
    __syncthreads();
  }
  if (t == 0) ws[OFF_STEP] = 0.9f / sqrtf(s_last);
}

// ---------------------------------------------------------------- K5: qC,qD per scenario
__global__ __launch_bounds__(512) void k_buildq(const float* __restrict__ w_err, float* ws) {
  const int s = blockIdx.x;
  const int t = threadIdx.x;
  __shared__ float wsh[NW];
  if (t < NW) wsh[t] = w_err[s*NW + t];
  __syncthreads();
  if (t < NLINE) {
    float wh = 0.f;
    #pragma unroll
    for (int w = 0; w < NW; ++w)
      wh = fmaf(wsh[w], ws[OFF_HWT + w*NLINE + t], wh);
    ws[OFF_QC + s*NLINE + t] = ws[OFF_FUP + t] - wh;
    ws[OFF_QD + s*NLINE + t] = ws[OFF_FDN + t] + wh;
  }
}

// ---------------------------------------------------------------- macro machinery for named registers
#define ROWK(M,jp) M(jp,0) M(jp,1) M(jp,2) M(jp,3) M(jp,4) M(jp,5) M(jp,6) \
                   M(jp,7) M(jp,8) M(jp,9) M(jp,10) M(jp,11) M(jp,12)
#define JPLIST(M) M(0) M(1) M(2) M(3) M(4) M(5) M(6) M(7)
#define KLIST(M)  M(0) M(1) M(2) M(3) M(4) M(5) M(6) M(7) M(8) M(9) M(10) M(11) M(12)
#define KLIST1(M) M(1) M(2) M(3) M(4) M(5) M(6) M(7) M(8) M(9) M(10) M(11) M(12)

#define DECLH(jp,k) unsigned int h##jp##_##k;
#define DECLROW(jp) ROWK(DECLH,jp)
#define LDH(jp,k)   h##jp##_##k = hpu[((((jp)*NUC) + cbase + (k)) << 5) + rg];
#define LDROW(jp)   ROWK(LDH,jp)
#define ACCD(k)     float acc##k = 0.f;
#define FMAA(jp,k)  acc##k = fmaf(blo(h##jp##_##k), u0, fmaf(bhi(h##jp##_##k), u1, acc##k));
#define PHA(jp)     { const float u0 = u_s[rg + ((jp) << 6)]; \
                      const float u1 = u_s[rg + ((jp) << 6) + 32]; ROWK(FMAA,jp) }
#define BFLY(k)     acc##k += __shfl_xor(acc##k, 16); acc##k += __shfl_xor(acc##k, 8); \
                    acc##k += __shfl_xor(acc##k, 4);  acc##k += __shfl_xor(acc##k, 2); \
                    acc##k += __shfl_xor(acc##k, 1);
#define SELK(k)     wv = (rg == (k)) ? acc##k : wv;
#define DECB(k)     float b##k = 0.f; { const int c = cbase + (k); \
                      const int ke = cus_s[c + 1]; \
                      for (int kk = cus_s[c]; kk < ke; ++kk) { const int comp = cul_s[kk]; \
                        b##k += (comp < NG) ? (z_s[comp] - z_s[NG + comp] - z_s[2*NG + comp]) \
                                            : z_s[200 + comp]; } }
#define FMAC(jp,k)  fp0 = fmaf(blo(h##jp##_##k), b##k, fp0); \
                    fp1 = fmaf(bhi(h##jp##_##k), b##k, fp1);
#define PHC(jp)     { float fp0 = 0.f, fp1 = 0.f; ROWK(FMAC,jp) \
                      fp0 += __shfl_xor(fp0, 32); fp1 += __shfl_xor(fp1, 32); \
                      if ((t & 32) == 0) { fpart[w][rg + ((jp) << 6)]      = fp0; \
                                           fpart[w][rg + ((jp) << 6) + 32] = fp1; } }

// ---------------------------------------------------------------- K6: PDHG, bf16-packed named-register tile
// 512 threads: rg = t&31, cg = t>>5. Rows l = rg + 32j (j<16) held as 8 row-pairs (l, l+32)
// packed 2xbf16/u32. 104 named u32 regs/thread.
// __launch_bounds__(512, 1): R4-R7 evidence shows arg2 acts as min BLOCKS/CU on this toolchain
// ((512,2)->128 VGPR cap, (1024,4)->64). (512,1) -> 8 waves/CU = 2/SIMD -> 256-reg cap.
__global__ __launch_bounds__(512, 1) void k_pdhg_reg(const float* __restrict__ ws,
                                                     float* __restrict__ out) {
  const int NUCr = ((const int*)(ws + OFF_NUC))[0];
  if (NUCr != NUC) return;          // bucket guard (uniform across grid)

  __shared__ float u_s[512], x_s[512], z_s[512];
  __shared__ float ts[NUC];
  __shared__ float fpart[8][512];
  __shared__ float yC[NLINE], yD[NLINE], qC[NLINE], qD[NLINE];
  __shared__ float yA[NG], yB[NG], qA[NG], qB[NG];
  __shared__ float sYE[1];
  __shared__ int c2u_s[NB], cus_s[NUPAD_MAX + 1], cul_s[NB];

  const int t = threadIdx.x;
  const int s = blockIdx.x;
  const int rg = t & 31, cg = t >> 5, w = t >> 6;
  const int cbase = cg * NC;
  const float step = ws[OFF_STEP];
  const float qE = ws[OFF_QE + s];

  // ---- init
  if (t < 512) { u_s[t] = 0.f; x_s[t] = 0.f; z_s[t] = 0.f; }
  if (t < NLINE) {
    yC[t] = 0.f; yD[t] = 0.f;
    qC[t] = ws[OFF_QC + s*NLINE + t];
    qD[t] = ws[OFF_QD + s*NLINE + t];
  }
  if (t < NG) { yA[t] = 0.f; yB[t] = 0.f; qA[t] = ws[OFF_RUP + t]; qB[t] = ws[OFF_RDN + t]; }
  if (t < NB) {
    c2u_s[t] = ((const int*)(ws + OFF_C2U))[t];
    cul_s[t] = ((const int*)(ws + OFF_CUL))[t];
  }
  if (t < NUPAD_MAX + 1) cus_s[t] = ((const int*)(ws + OFF_CUS))[t];
  if (t == 0) sYE[0] = 0.f;

  // ---- load packed tile into 104 named registers (coalesced over rg)
  JPLIST(DECLROW)
  {
    const unsigned int* __restrict__ hpu = (const unsigned int*)(ws + OFF_HSPB);
    JPLIST(LDROW)
  }
  __syncthreads();

  for (int it = 0; it < NITERS; ++it) {
    // ---- Phase A: ts[c] = sum_l Hs[l,c]*u[l]; rows reduced by 32-lane butterfly
    {
      KLIST(ACCD)
      JPLIST(PHA)
      KLIST(BFLY)
      float wv = acc0;
      KLIST1(SELK)
      if (rg < NC) ts[cbase + rg] = wv;
    }
    __syncthreads();

    // ---- Phase B: x-update
    if (t < NX) {
      const int cc = (t < NB) ? (t % NG) : (t - 200);
      const float tg = ts[c2u_s[cc]];
      const float yE = sYE[0];
      float yK;
      if (t < NG)        yK = yA[t] + tg + yE;
      else if (t < 2*NG) yK = yB[t - NG] - tg - yE;
      else if (t < NB)   yK = -tg - yE;
      else               yK = tg + yE;
      const float cj = (t < 2*NG) ? 0.f : CVIOL;
      const float xo = x_s[t];
      const float x1 = fmaxf(xo - step*(cj + yK), 0.f);
      z_s[t] = 2.f*x1 - xo;
      x_s[t] = x1;
    }
    __syncthreads();

    // ---- Phase C: in-thread busz for own 13 cols, then f[l] partials
    {
      KLIST(DECB)
      JPLIST(PHC)
    }
    __syncthreads();

    // ---- Phase D: y-updates + u for next iter; yA/yB folded in; E in wave 7
    if (t < NLINE) {
      float cv = 0.f;
      #pragma unroll
      for (int g = 0; g < 8; ++g) cv += fpart[g][t];
      const float cy = fmaxf(yC[t] + step*( cv - qC[t]), 0.f);
      const float dy = fmaxf(yD[t] + step*(-cv - qD[t]), 0.f);
      yC[t] = cy; yD[t] = dy; u_s[t] = cy - dy;
      if (t < NG)             yA[t]      = fmaxf(yA[t]      + step*(z_s[t]   - qA[t]),      0.f);
      else if (t < 2*NG)      yB[t - NG] = fmaxf(yB[t - NG] + step*(z_s[t]   - qB[t - NG]), 0.f);
    }
    if (t >= 448) {                     // wave 7: E = sum(sign * z)
      const int lane = t - 448;
      float e = 0.f;
      #pragma unroll
      for (int m = 0; m < 8; ++m) {
        const int idx = lane + (m << 6);
        const float zv = z_s[idx];
        e += (idx < NG || idx >= NB) ? zv : -zv;
      }
      e += __shfl_xor(e, 32); e += __shfl_xor(e, 16); e += __shfl_xor(e, 8);
      e += __shfl_xor(e, 4);  e += __shfl_xor(e, 2);  e += __shfl_xor(e, 1);
      if (t == 511) sYE[0] += step*(e - qE);
    }
    __syncthreads();
  }

  // ---- cost = CVIOL * sum(x[200:500])
  if (t < 64) {
    float p = 0.f;
    for (int k = 200 + t; k < NX; k += 64) p += x_s[k];
    for (int o = 32; o; o >>= 1) p += __shfl_down(p, o);
    if (t == 0) out[s] = CVIOL * p;
  }
}

// ---------------------------------------------------------------- K6fb: streaming fallback (NU > 208)
__global__ __launch_bounds__(1024) void k_pdhg_fb(const float* __restrict__ ws,
                                                  float* __restrict__ out) {
  const int NUCr = ((const int*)(ws + OFF_NUC))[0];
  if (NUCr != 0) return;
  const int NUPr = ((const int*)(ws + OFF_NUP))[0];

  __shared__ float u_s[512], x_s[512], z_s[512], cv_s[512];
  __shared__ float ts[NUPAD_MAX], busz[NUPAD_MAX];
  __shared__ float yC[NLINE], yD[NLINE], qC[NLINE], qD[NLINE];
  __shared__ float yA[NG], yB[NG], qA[NG], qB[NG];
  __shared__ float sE[1], sYE[1];
  __shared__ int c2u_s[NB], cus_s[NUPAD_MAX + 1], cul_s[NB];

  const int t = threadIdx.x;
  const int s = blockIdx.x;
  const float step = ws[OFF_STEP];
  const float qE = ws[OFF_QE + s];
  const float* __restrict__ HST = ws + OFF_HST;

  if (t < 512) { u_s[t] = 0.f; x_s[t] = 0.f; z_s[t] = 0.f; }
  if (t < NLINE) {
    yC[t] = 0.f; yD[t] = 0.f;
    qC[t] = ws[OFF_QC + s*NLINE + t];
    qD[t] = ws[OFF_QD + s*NLINE + t];
  }
  if (t < NG) { yA[t] = 0.f; yB[t] = 0.f; qA[t] = ws[OFF_RUP + t]; qB[t] = ws[OFF_RDN + t]; }
  if (t < NB) {
    c2u_s[t] = ((const int*)(ws + OFF_C2U))[t];
    cul_s[t] = ((const int*)(ws + OFF_CUL))[t];
  }
  if (t < NUPAD_MAX + 1) cus_s[t] = ((const int*)(ws + OFF_CUS))[t];
  if (t == 0) { sE[0] = 0.f; sYE[0] = 0.f; }
  __syncthreads();

  const int w = t >> 6, lane = t & 63;

  for (int it = 0; it < NITERS; ++it) {
    for (int c = w; c < NUPr; c += 16) {
      float a = 0.f;
      #pragma unroll
      for (int m = 0; m < 8; ++m) { const int l = lane + (m << 6); a = fmaf(HST[c*512 + l], u_s[l], a); }
      a += __shfl_xor(a, 32); a += __shfl_xor(a, 16); a += __shfl_xor(a, 8);
      a += __shfl_xor(a, 4);  a += __shfl_xor(a, 2);  a += __shfl_xor(a, 1);
      if (lane == 0) ts[c] = a;
    }
    __syncthreads();
    if (t < NX) {
      const int cc = (t < NB) ? (t % NG) : (t - 200);
      const float tg = ts[c2u_s[cc]];
      const float yE = sYE[0];
      float yK;
      if (t < NG)        yK = yA[t] + tg + yE;
      else if (t < 2*NG) yK = yB[t - NG] - tg - yE;
      else if (t < NB)   yK = -tg - yE;
      else               yK = tg + yE;
      const float cj = (t < 2*NG) ? 0.f : CVIOL;
      const float xo = x_s[t];
      const float x1 = fmaxf(xo - step*(cj + yK), 0.f);
      z_s[t] = 2.f*x1 - xo;
      x_s[t] = x1;
    }
    __syncthreads();
    if (t < NUPr) {
      float a = 0.f;
      const int k0 = cus_s[t], k1 = cus_s[t + 1];
      for (int k = k0; k < k1; ++k) {
        const int c = cul_s[k];
        a += (c < NG) ? (z_s[c] - z_s[NG + c] - z_s[2*NG + c]) : z_s[200 + c];
      }
      busz[t] = a;
    } else if (t >= 768 && t < 832) {
      const int ln = t - 768;
      float e = 0.f;
      for (int idx = ln; idx < NX; idx += 64) {
        const float zv = z_s[idx];
        e += (idx < NG || idx >= NB) ? zv : -zv;
      }
      e += __shfl_xor(e, 32); e += __shfl_xor(e, 16); e += __shfl_xor(e, 8);
      e += __shfl_xor(e, 4);  e += __shfl_xor(e, 2);  e += __shfl_xor(e, 1);
      if (ln == 0) sE[0] = e;
    }
    __syncthreads();
    if (t < 512) {
      float a = 0.f;
      for (int c = 0; c < NUPr; ++c) a = fmaf(HST[c*512 + t], busz[c], a);
      cv_s[t] = a;
    }
    __syncthreads();
    if (t < NLINE) {
      const float cv = cv_s[t];
      const float cy = fmaxf(yC[t] + step*( cv - qC[t]), 0.f);
      const float dy = fmaxf(yD[t] + step*(-cv - qD[t]), 0.f);
      yC[t] = cy; yD[t] = dy; u_s[t] = cy - dy;
    } else if (t >= 512 && t < 612) {
      const int g = t - 512;
      yA[g] = fmaxf(yA[g] + step*(z_s[g] - qA[g]), 0.f);
    } else if (t >= 612 && t < 712) {
      const int g = t - 612;
      yB[g] = fmaxf(yB[g] + step*(z_s[NG + g] - qB[g]), 0.f);
    } else if (t == 1023) {
      sYE[0] += step*(sE[0] - qE);
    }
    __syncthreads();
  }
  if (t < 64) {
    float p = 0.f;
    for (int k = 200 + t; k < NX; k += 64) p += x_s[k];
    for (int o = 32; o; o >>= 1) p += __shfl_down(p, o);
    if (t == 0) out[s] = CVIOL * p;
  }
}

extern "C" void kernel_launch(void* const* d_in, const int* in_sizes, int n_in,
                              void* d_out, int out_size, void* d_ws, size_t ws_size,
                              hipStream_t stream) {
  (void)in_sizes; (void)n_in; (void)out_size; (void)ws_size;
  const float* p_da      = (const float*)d_in[0];
  const float* r_up_hat  = (const float*)d_in[1];
  const float* r_dn_hat  = (const float*)d_in[2];
  const float* fup_hat   = (const float*)d_in[3];
  const float* fdn_hat   = (const float*)d_in[4];
  const float* w_err     = (const float*)d_in[5];
  const float* Pmax      = (const float*)d_in[6];
  const float* PTDF      = (const float*)d_in[7];
  const float* nG        = (const float*)d_in[8];
  const float* nL        = (const float*)d_in[9];
  const float* nW        = (const float*)d_in[10];
  float* ws  = (float*)d_ws;
  float* out = (float*)d_out;

  hipLaunchKernelGGL(k_pre,    dim3(1),   dim3(512),  0, stream,
                     p_da, r_up_hat, r_dn_hat, fup_hat, fdn_hat, w_err, Pmax, nG, nL, nW, ws);
  hipLaunchKernelGGL(k_buildH, dim3(500), dim3(512),  0, stream, PTDF, ws);
  hipLaunchKernelGGL(k_buildB, dim3(300), dim3(320),  0, stream, ws);
  hipLaunchKernelGGL(k_power,  dim3(1),   dim3(1024), 0, stream, ws);
  hipLaunchKernelGGL(k_buildq, dim3(128), dim3(512),  0, stream, w_err, ws);
  hipLaunchKernelGGL(k_pdhg_reg, dim3(128), dim3(512), 0, stream, ws, out);
  hipLaunchKernelGGL(k_pdhg_fb, dim3(128), dim3(1024), 0, stream, ws, out);
}